// Round 18
// baseline (138.724 us; speedup 1.0000x reference)
//
#include <hip/hip_runtime.h>

#define N_DIM 512
#define M_DIM 512
#define NOCT 64             // 512 rows as 64 row-octads
#define TSTEPS 128          // 64 octads + 63 skew, padded even
#define SLOT8 8192          // bf16 octad slot: 8 rows x 64 lanes x 16B
#define DDEPTH 4            // DP ring depth
#define RING8 (DDEPTH * SLOT8)              // 32 KB
#define SIGMA_MAX (TSTEPS + DDEPTH)         // 132 input slots
#define BSTRIDE (N_DIM * M_DIM)
#define GSTR_O (NOCT * 64)                  // 4096 (octad path)
#define GSTR_Q (128 * 64)                   // 8192 (fallback path)
#define DSKEW_B ((size_t)SIGMA_MAX * SLOT8)
#define ESKEW_B ((size_t)TSTEPS * SLOT8)
#define LN2F 0.6931471805599453f
// fallback-path constants (f32 direct kernel)
#define DEPTH 4
#define SLOT_BYTES 8192
#define RING_BYTES (DEPTH * SLOT_BYTES)
#define ROW_BYTES 2048
#define ROW_MAX (511 * 2048)

#define AS1 __attribute__((address_space(1)))
#define AS3 __attribute__((address_space(3)))

__device__ inline unsigned pkbf16(float lo, float hi) {
    unsigned r; asm("v_cvt_pk_bf16_f32 %0, %1, %2" : "=v"(r) : "v"(lo), "v"(hi)); return r;
}
__device__ inline float ubf_lo(unsigned u) { return __int_as_float((int)(u << 16)); }
__device__ inline float ubf_hi(unsigned u) { return __int_as_float((int)(u & 0xffff0000u)); }

// ---- pass 1: exp(-D) -> bf16, octad-skewed (slot, row-chunk, lane) ----
// Slot sigma = t + l; chunk ch in [0,8) = row 8t+ch; lane l: 16B = 8 bf16.
// Tile = 4 octads (32 rows x 512 cols), coalesced reads.
__global__ __launch_bounds__(256) void skew_pre(const float* __restrict__ D,
                                                char* __restrict__ Dsk) {
    const int b  = blockIdx.y;
    const int t0 = blockIdx.x << 2;           // 4 octads per tile
    __shared__ float4 tile[4096];             // 32 rows x 128 f4
    const int tid = threadIdx.x;

    const float4* src = (const float4*)(D + (size_t)b * BSTRIDE) + ((size_t)t0 << 10);
    #pragma unroll
    for (int w = 0; w < 16; ++w) {
        const int idx = (w << 8) + tid;
        const float4 v = src[idx];
        tile[idx] = make_float4(__expf(-v.x), __expf(-v.y), __expf(-v.z), __expf(-v.w));
    }
    __syncthreads();

    char* dst = Dsk + (size_t)b * DSKEW_B;
    #pragma unroll
    for (int w = 0; w < 9; ++w) {
        const int w2 = (w << 8) + tid;        // [0, 2304)
        const int li = w2 & 3;
        const int ch = (w2 >> 2) & 7;
        const int si = w2 >> 5;               // sigma - t0, [0, 72)
        const int lmin = max(0, si - 3);
        const int l = lmin + li;
        if (si < 67 && l <= min(63, si)) {
            const int ti = si - l;            // [0, 4)
            const int base = (((ti << 3) + ch) << 7) + (l << 1);
            const float4 a = tile[base];
            const float4 c = tile[base + 1];
            uint4 o;
            o.x = pkbf16(a.x, a.y); o.y = pkbf16(a.z, a.w);
            o.z = pkbf16(c.x, c.y); o.w = pkbf16(c.z, c.w);
            *(uint4*)(dst + (size_t)(t0 + si) * SLOT8 + (ch << 10) + (l << 4)) = o;
        }
    }
}

// ---- pass 3: un-skew bf16 E + R = g - log(E) ----
__global__ __launch_bounds__(256) void unskew_post(const char* __restrict__ Esk,
                                                   const float* __restrict__ gm,
                                                   float* __restrict__ R) {
    const int b  = blockIdx.y;
    const int t0 = blockIdx.x << 2;
    __shared__ float4 tile[4096];
    const int tid = threadIdx.x;

    const char* srcE = Esk + (size_t)b * ESKEW_B;
    #pragma unroll
    for (int w = 0; w < 9; ++w) {
        const int w2 = (w << 8) + tid;
        const int li = w2 & 3;
        const int ch = (w2 >> 2) & 7;
        const int si = w2 >> 5;
        const int lmin = max(0, si - 3);
        const int l = lmin + li;
        if (si < 67 && l <= min(63, si)) {
            const int ti = si - l;
            const uint4 v = *(const uint4*)(srcE + (size_t)(t0 + si) * SLOT8
                                            + (ch << 10) + (l << 4));
            const int base = (((ti << 3) + ch) << 7) + (l << 1);
            tile[base]     = make_float4(ubf_lo(v.x), ubf_hi(v.x), ubf_lo(v.y), ubf_hi(v.y));
            tile[base + 1] = make_float4(ubf_lo(v.z), ubf_hi(v.z), ubf_lo(v.w), ubf_hi(v.w));
        }
    }
    __syncthreads();

    float* dstR = R + (size_t)b * BSTRIDE;
    const float* gmb = gm + b * GSTR_O;
    #pragma unroll
    for (int w = 0; w < 16; ++w) {
        const int idx = (w << 8) + tid;
        const int rit = idx >> 7;             // 0..31
        const int c4  = idx & 127;
        const int oc  = t0 + (rit >> 3);
        const float g = gmb[(oc << 6) + (c4 >> 1)];
        const float4 v = tile[idx];
        *(float4*)(dstR + (((size_t)(t0 << 3) + rit) << 9) + (c4 << 2)) =
            make_float4(g - __logf(v.x), g - __logf(v.y), g - __logf(v.z), g - __logf(v.w));
    }
}

// ---- fallback post (plain layout, quad gm) ----
__global__ __launch_bounds__(256) void log_post_plain(float4* __restrict__ E4,
                                                      const float* __restrict__ gm, int n4) {
    int i = blockIdx.x * blockDim.x + threadIdx.x;
    const int stride = gridDim.x * blockDim.x;
    for (; i < n4; i += stride) {
        const int b   = i >> 16;
        const int rem = i & 65535;
        const int row = rem >> 7;
        const int c4  = rem & 127;
        const float g = gm[(b << 13) + ((row >> 2) << 6) + (c4 >> 1)];
        const float4 v = E4[i];
        E4[i] = make_float4(g - __logf(v.x), g - __logf(v.y),
                            g - __logf(v.z), g - __logf(v.w));
    }
}

// DPP wave-shift-right-by-1 (lane 0 gets 0 = BIG boundary).
__device__ inline float shup1(float x) {
    int r = __builtin_amdgcn_update_dpp(0, __float_as_int(x), 0x138, 0xf, 0xf, true);
    return __int_as_float(r);
}
__device__ inline int shup1i(int x) {
    return __builtin_amdgcn_update_dpp(0, x, 0x138, 0xf, 0xf, true);
}
__device__ inline int fr_exp(float x) {
    int e; asm("v_frexp_exp_i32_f32 %0, %1" : "=v"(e) : "v"(x)); return e;
}
__device__ inline float ldx(float x, int k) {
    float r; asm("v_ldexp_f32 %0, %1, %2" : "=v"(r) : "v"(x), "v"(k)); return r;
}

// ---- pass 2: DP wave, 8 rows/step (octads), 128 steps, bf16 plane ----
__global__ __launch_bounds__(64, 1) void softdtw_dp_skew(const char* __restrict__ Dsk,
                                                         char* __restrict__ Esk,
                                                         float* __restrict__ gmap) {
    const int b = blockIdx.x;
    const int l = threadIdx.x;
    const int laneB16 = l << 4;

    const char* __restrict__ DskB = Dsk + (size_t)b * DSKEW_B;
    char*       __restrict__ EskB = Esk + (size_t)b * ESKEW_B;
    float*      __restrict__ gm   = gmap + (size_t)b * GSTR_O;

    __shared__ char ring[RING8] __attribute__((aligned(16)));
    const unsigned ring_base = (unsigned)(size_t)(AS3 char*)ring;

    float Ep[8];                    // row H of previous octad
    #pragma unroll
    for (int k = 0; k < 8; ++k) Ep[k] = 0.0f;
    float fQ = 0.0f;
    int   KG = 0, KE = 0, Kh = 0;
    float ex0 = 0.0f, ex1 = 0.0f, ex2 = 0.0f, ex3 = 0.0f;   // exported E[7] rows 0..7
    float ex4 = 0.0f, ex5 = 0.0f, ex6 = 0.0f, ex7 = 0.0f;
    float E7hH = 0.0f;              // history: neighbor's row-H export, one step ago

    int dsk_off = DDEPTH * SLOT8;   // DMA source for step s (slot s+4)
    int es_off  = 0;                // store offset (slot s)

    uint4 P[8], Nx[8];
    #pragma unroll
    for (int ch = 0; ch < 8; ++ch)
        P[ch] = *(const uint4*)(DskB + ch * 1024 + laneB16);
    #pragma unroll
    for (int sig = 1; sig < DDEPTH; ++sig) {
        const char* gp = DskB + sig * SLOT8 + laneB16;
        #pragma unroll
        for (int ch = 0; ch < 8; ++ch)
            __builtin_amdgcn_global_load_lds((const AS1 void*)(gp + ch * 1024),
                                             (AS3 void*)(ring + sig * SLOT8 + ch * 1024),
                                             16, 0, 0);
    }
    asm volatile("s_waitcnt vmcnt(0)" ::: "memory");

    // one row: E = end*(eLeft_chain + Q), Q from prev row (+ diag boundary)
    auto dorow = [&](const uint4 q, float eDiag, float eLeft,
                     const float* Eprev, float* Eo) {
        float end[8];
        end[0] = ubf_lo(q.x); end[1] = ubf_hi(q.x);
        end[2] = ubf_lo(q.y); end[3] = ubf_hi(q.y);
        end[4] = ubf_lo(q.z); end[5] = ubf_hi(q.z);
        end[6] = ubf_lo(q.w); end[7] = ubf_hi(q.w);
        float Q[8];
        Q[0] = eDiag + Eprev[0];
        #pragma unroll
        for (int c = 1; c < 8; ++c) Q[c] = Eprev[c - 1] + Eprev[c];
        float e = eLeft;
        #pragma unroll
        for (int c = 0; c < 8; ++c) {
            e = __builtin_fmaf(end[c], e, end[c] * Q[c]);
            Eo[c] = e;
        }
    };

    auto step = [&](int s, uint4 (&cur)[8], uint4 (&nxt)[8]) {
        // (1) DMA slot s+4 into phys slot s&3 (8 x 1KB coalesced)
        {
            const unsigned wo = ((unsigned)s & (DDEPTH - 1)) * SLOT8;   // (s+4)%4
            const char* gp = DskB + dsk_off + laneB16;
            #pragma unroll
            for (int ch = 0; ch < 8; ++ch)
                __builtin_amdgcn_global_load_lds((const AS1 void*)(gp + ch * 1024),
                                                 (AS3 void*)(ring + wo + ch * 1024), 16, 0, 0);
            dsk_off += SLOT8;
        }
        // (2) counted vmcnt: slot s+1's DMA (step s-3) has
        //     st(s-3)9 + D(s-2)8 + st(s-2)9 + D(s-1)8 + st(s-1)9 + D(s)8 = 51 newer ops
        asm volatile("s_waitcnt vmcnt(51)" ::: "memory");

        // (3) boundary from lane l-1 via DPP (8 row exports + frame)
        const float E7s0 = shup1(ex0);
        const float E7s1 = shup1(ex1);
        const float E7s2 = shup1(ex2);
        const float E7s3 = shup1(ex3);
        const float E7s4 = shup1(ex4);
        const float E7s5 = shup1(ex5);
        const float E7s6 = shup1(ex6);
        const float E7s7 = shup1(ex7);
        const int   Ks   = shup1i(KE);

        // (4) issue ds_read of next slot (8 x b128)
        const unsigned raddr = ring_base
                             + (unsigned)((s + 1) & (DDEPTH - 1)) * SLOT8
                             + (unsigned)laneB16;
        asm volatile("ds_read_b128 %0, %8 offset:0\n\t"
                     "ds_read_b128 %1, %8 offset:1024\n\t"
                     "ds_read_b128 %2, %8 offset:2048\n\t"
                     "ds_read_b128 %3, %8 offset:3072\n\t"
                     "ds_read_b128 %4, %8 offset:4096\n\t"
                     "ds_read_b128 %5, %8 offset:5120\n\t"
                     "ds_read_b128 %6, %8 offset:6144\n\t"
                     "ds_read_b128 %7, %8 offset:7168"
                     : "=&v"(nxt[0]), "=&v"(nxt[1]), "=&v"(nxt[2]), "=&v"(nxt[3]),
                       "=&v"(nxt[4]), "=&v"(nxt[5]), "=&v"(nxt[6]), "=&v"(nxt[7])
                     : "v"(raddr));

        // (5) wait only for PREVIOUS step's 8 reads (cur); fence consumption
        asm volatile("s_waitcnt lgkmcnt(8)" ::: "memory");
        __builtin_amdgcn_sched_barrier(0);

        // (6) compute octad t = s - l
        const int t = s - l;
        if (t >= 0 && t < NOCT) {
            const bool is0    = (t == 0);
            const bool origin = is0 && (l == 0);
            int K = is0 ? (Ks - fr_exp(E7s0)) : KG;
            K = origin ? 0 : K;
            const float fq = is0 ? 0.0f : fQ;
            const int dKs = K - Ks;
            const int dKh = K - Kh;

            const float eL0 = ldx(E7s0, dKs);
            const float eL1 = ldx(E7s1, dKs);
            const float eL2 = ldx(E7s2, dKs);
            const float eL3 = ldx(E7s3, dKs);
            const float eL4 = ldx(E7s4, dKs);
            const float eL5 = ldx(E7s5, dKs);
            const float eL6 = ldx(E7s6, dKs);
            const float eL7 = ldx(E7s7, dKs);
            float eD0 = ldx(E7hH, dKh);
            eD0 = is0 ? 0.0f : eD0;
            eD0 = origin ? 1.0f : eD0;

            float Fp[8];
            #pragma unroll
            for (int c = 0; c < 8; ++c) Fp[c] = fq * Ep[c];

            char* sb = EskB + es_off + laneB16;
            float Ea[8], Eb[8];
            uint4 o;

            dorow(cur[0], eD0, eL0, Fp, Ea);
            o.x = pkbf16(Ea[0], Ea[1]); o.y = pkbf16(Ea[2], Ea[3]);
            o.z = pkbf16(Ea[4], Ea[5]); o.w = pkbf16(Ea[6], Ea[7]);
            *(uint4*)(sb) = o;  ex0 = Ea[7];

            dorow(cur[1], eL0, eL1, Ea, Eb);
            o.x = pkbf16(Eb[0], Eb[1]); o.y = pkbf16(Eb[2], Eb[3]);
            o.z = pkbf16(Eb[4], Eb[5]); o.w = pkbf16(Eb[6], Eb[7]);
            *(uint4*)(sb + 1024) = o;  ex1 = Eb[7];

            dorow(cur[2], eL1, eL2, Eb, Ea);
            o.x = pkbf16(Ea[0], Ea[1]); o.y = pkbf16(Ea[2], Ea[3]);
            o.z = pkbf16(Ea[4], Ea[5]); o.w = pkbf16(Ea[6], Ea[7]);
            *(uint4*)(sb + 2048) = o;  ex2 = Ea[7];

            dorow(cur[3], eL2, eL3, Ea, Eb);
            o.x = pkbf16(Eb[0], Eb[1]); o.y = pkbf16(Eb[2], Eb[3]);
            o.z = pkbf16(Eb[4], Eb[5]); o.w = pkbf16(Eb[6], Eb[7]);
            *(uint4*)(sb + 3072) = o;  ex3 = Eb[7];

            dorow(cur[4], eL3, eL4, Eb, Ea);
            o.x = pkbf16(Ea[0], Ea[1]); o.y = pkbf16(Ea[2], Ea[3]);
            o.z = pkbf16(Ea[4], Ea[5]); o.w = pkbf16(Ea[6], Ea[7]);
            *(uint4*)(sb + 4096) = o;  ex4 = Ea[7];

            dorow(cur[5], eL4, eL5, Ea, Eb);
            o.x = pkbf16(Eb[0], Eb[1]); o.y = pkbf16(Eb[2], Eb[3]);
            o.z = pkbf16(Eb[4], Eb[5]); o.w = pkbf16(Eb[6], Eb[7]);
            *(uint4*)(sb + 5120) = o;  ex5 = Eb[7];

            dorow(cur[6], eL5, eL6, Eb, Ea);
            o.x = pkbf16(Ea[0], Ea[1]); o.y = pkbf16(Ea[2], Ea[3]);
            o.z = pkbf16(Ea[4], Ea[5]); o.w = pkbf16(Ea[6], Ea[7]);
            *(uint4*)(sb + 6144) = o;  ex6 = Ea[7];

            dorow(cur[7], eL6, eL7, Ea, Eb);
            o.x = pkbf16(Eb[0], Eb[1]); o.y = pkbf16(Eb[2], Eb[3]);
            o.z = pkbf16(Eb[4], Eb[5]); o.w = pkbf16(Eb[6], Eb[7]);
            *(uint4*)(sb + 7168) = o;  ex7 = Eb[7];

            gm[(t << 6) + l] = (float)K * LN2F;

            // frame update for next octad
            const int ed = fr_exp(Eb[0]);
            KG = K - ed;
            fQ = ldx(1.0f, -ed);
            KE = K;
            #pragma unroll
            for (int c = 0; c < 8; ++c) Ep[c] = Eb[c];
        }

        // (7) history + offsets
        E7hH = E7s7;
        Kh   = Ks;
        es_off += SLOT8;
    };

    for (int s = 0; s < TSTEPS; s += 2) {
        step(s,     P,  Nx);
        step(s + 1, Nx, P);
    }
}

// ---- fallback: direct DP (in-kernel exp, scattered), plain f32 layout ----
__global__ __launch_bounds__(64, 1) void softdtw_dp_direct(const float* __restrict__ Dsrc,
                                                           float* __restrict__ Eout,
                                                           float* __restrict__ gmap) {
    const int b     = blockIdx.x;
    const int l     = threadIdx.x;
    const int laneB = l << 5;
    const float* __restrict__ Db = Dsrc + (size_t)b * BSTRIDE;
    float*       __restrict__ Rb = Eout + (size_t)b * BSTRIDE;
    float*       __restrict__ gm = gmap + (size_t)b * GSTR_Q;
    __shared__ char ring[RING_BYTES] __attribute__((aligned(16)));
    const unsigned ring_base = (unsigned)(size_t)(AS3 char*)ring;

    float Ep[8];
    #pragma unroll
    for (int k = 0; k < 8; ++k) Ep[k] = 0.0f;
    float fQ = 0.0f;
    int KG = 0, KE = 0, Kh = 0;
    float expA7 = 0.0f, expB7 = 0.0f, expC7 = 0.0f, expD7 = 0.0f;
    float E7hD = 0.0f;
    int raw[4];
    #pragma unroll
    for (int k = 0; k < 4; ++k) raw[k] = (16 + k) * ROW_BYTES - (l << 13);
    int soff = -(l << 13);

    float4 P[8], Nx[8];
    #pragma unroll
    for (int row = 0; row < 4; ++row) {
        const int r = min(max(-4 * l + row, 0), N_DIM - 1);
        P[2 * row]     = *(const float4*)(Db + (size_t)r * M_DIM + (l << 3));
        P[2 * row + 1] = *(const float4*)(Db + (size_t)r * M_DIM + (l << 3) + 4);
    }
    #pragma unroll
    for (int sig = 1; sig < DEPTH; ++sig) {
        const unsigned wo = (unsigned)sig * SLOT_BYTES;
        #pragma unroll
        for (int k = 0; k < 4; ++k) {
            const int cl = min(max((4 * (sig - l) + k) * ROW_BYTES, 0), ROW_MAX);
            const char* gp = (const char*)Db + cl + laneB;
            __builtin_amdgcn_global_load_lds((const AS1 void*)gp,
                                             (AS3 void*)(ring + wo + (2 * k) * 1024), 16, 0, 0);
            __builtin_amdgcn_global_load_lds((const AS1 void*)(gp + 16),
                                             (AS3 void*)(ring + wo + (2 * k + 1) * 1024), 16, 0, 0);
        }
    }
    asm volatile("s_waitcnt vmcnt(0)" ::: "memory");

    auto rowfma = [&](const float* endv, float eLeft, const float* Q, float* E) {
        float e = eLeft;
        #pragma unroll
        for (int c = 0; c < 8; ++c) {
            e = __builtin_fmaf(endv[c], e, endv[c] * Q[c]);
            E[c] = e;
        }
    };

    auto step = [&](int s, float4 (&cur)[8], float4 (&nxt)[8]) {
        {
            const unsigned wo = ((unsigned)(s + DEPTH) & (DEPTH - 1)) * SLOT_BYTES;
            #pragma unroll
            for (int k = 0; k < 4; ++k) {
                const int cl = min(max(raw[k], 0), ROW_MAX);
                const char* gp = (const char*)Db + cl + laneB;
                __builtin_amdgcn_global_load_lds((const AS1 void*)gp,
                                                 (AS3 void*)(ring + wo + (2 * k) * 1024), 16, 0, 0);
                __builtin_amdgcn_global_load_lds((const AS1 void*)(gp + 16),
                                                 (AS3 void*)(ring + wo + (2 * k + 1) * 1024), 16, 0, 0);
                raw[k] += 4 * ROW_BYTES;
            }
        }
        asm volatile("s_waitcnt vmcnt(51)" ::: "memory");
        const float E7sA = shup1(expA7);
        const float E7sB = shup1(expB7);
        const float E7sC = shup1(expC7);
        const float E7sD = shup1(expD7);
        const int   Ks   = shup1i(KE);
        const unsigned raddr = ring_base
                             + (unsigned)((s + 1) & (DEPTH - 1)) * SLOT_BYTES
                             + (unsigned)l * 16u;
        asm volatile("ds_read_b128 %0, %8 offset:0\n\t"
                     "ds_read_b128 %1, %8 offset:1024\n\t"
                     "ds_read_b128 %2, %8 offset:2048\n\t"
                     "ds_read_b128 %3, %8 offset:3072\n\t"
                     "ds_read_b128 %4, %8 offset:4096\n\t"
                     "ds_read_b128 %5, %8 offset:5120\n\t"
                     "ds_read_b128 %6, %8 offset:6144\n\t"
                     "ds_read_b128 %7, %8 offset:7168"
                     : "=&v"(nxt[0]), "=&v"(nxt[1]), "=&v"(nxt[2]), "=&v"(nxt[3]),
                       "=&v"(nxt[4]), "=&v"(nxt[5]), "=&v"(nxt[6]), "=&v"(nxt[7])
                     : "v"(raddr));
        asm volatile("s_waitcnt lgkmcnt(8)" ::: "memory");
        __builtin_amdgcn_sched_barrier(0);
        const int t = s - l;
        if (t >= 0 && t < 128) {
            const float endA[8] = {__expf(-cur[0].x), __expf(-cur[0].y), __expf(-cur[0].z), __expf(-cur[0].w),
                                   __expf(-cur[1].x), __expf(-cur[1].y), __expf(-cur[1].z), __expf(-cur[1].w)};
            const float endB[8] = {__expf(-cur[2].x), __expf(-cur[2].y), __expf(-cur[2].z), __expf(-cur[2].w),
                                   __expf(-cur[3].x), __expf(-cur[3].y), __expf(-cur[3].z), __expf(-cur[3].w)};
            const float endC[8] = {__expf(-cur[4].x), __expf(-cur[4].y), __expf(-cur[4].z), __expf(-cur[4].w),
                                   __expf(-cur[5].x), __expf(-cur[5].y), __expf(-cur[5].z), __expf(-cur[5].w)};
            const float endD[8] = {__expf(-cur[6].x), __expf(-cur[6].y), __expf(-cur[6].z), __expf(-cur[6].w),
                                   __expf(-cur[7].x), __expf(-cur[7].y), __expf(-cur[7].z), __expf(-cur[7].w)};
            const bool is0    = (t == 0);
            const bool origin = is0 && (l == 0);
            int K = is0 ? (Ks - fr_exp(E7sA)) : KG;
            K = origin ? 0 : K;
            const float fq = is0 ? 0.0f : fQ;
            const int dKs = K - Ks;
            const int dKh = K - Kh;
            const float eLA = ldx(E7sA, dKs);
            const float eLB = ldx(E7sB, dKs);
            const float eLC = ldx(E7sC, dKs);
            const float eLD = ldx(E7sD, dKs);
            float eDA0 = ldx(E7hD, dKh);
            eDA0 = is0 ? 0.0f : eDA0;
            eDA0 = origin ? 1.0f : eDA0;
            float QA[8];
            QA[0] = eDA0 + fq * Ep[0];
            #pragma unroll
            for (int c = 1; c < 8; ++c) QA[c] = fq * (Ep[c - 1] + Ep[c]);
            float EA[8]; rowfma(endA, eLA, QA, EA);
            float QB[8];
            QB[0] = eLA + EA[0];
            #pragma unroll
            for (int c = 1; c < 8; ++c) QB[c] = EA[c - 1] + EA[c];
            float EB[8]; rowfma(endB, eLB, QB, EB);
            float QC[8];
            QC[0] = eLB + EB[0];
            #pragma unroll
            for (int c = 1; c < 8; ++c) QC[c] = EB[c - 1] + EB[c];
            float EC[8]; rowfma(endC, eLC, QC, EC);
            float QD[8];
            QD[0] = eLC + EC[0];
            #pragma unroll
            for (int c = 1; c < 8; ++c) QD[c] = EC[c - 1] + EC[c];
            float ED[8]; rowfma(endD, eLD, QD, ED);
            char* sb  = (char*)Rb + soff + laneB;
            char* sb2 = sb + 4096;
            *(float4*)(sb)         = make_float4(EA[0], EA[1], EA[2], EA[3]);
            *(float4*)(sb + 16)    = make_float4(EA[4], EA[5], EA[6], EA[7]);
            *(float4*)(sb + 2048)  = make_float4(EB[0], EB[1], EB[2], EB[3]);
            *(float4*)(sb + 2064)  = make_float4(EB[4], EB[5], EB[6], EB[7]);
            *(float4*)(sb2)        = make_float4(EC[0], EC[1], EC[2], EC[3]);
            *(float4*)(sb2 + 16)   = make_float4(EC[4], EC[5], EC[6], EC[7]);
            *(float4*)(sb2 + 2048) = make_float4(ED[0], ED[1], ED[2], ED[3]);
            *(float4*)(sb2 + 2064) = make_float4(ED[4], ED[5], ED[6], ED[7]);
            gm[(t << 6) + l] = (float)K * LN2F;
            const int ed = fr_exp(ED[0]);
            KG = K - ed;
            fQ = ldx(1.0f, -ed);
            KE = K;
            #pragma unroll
            for (int c = 0; c < 8; ++c) Ep[c] = ED[c];
            expA7 = EA[7]; expB7 = EB[7]; expC7 = EC[7]; expD7 = ED[7];
        }
        E7hD = E7sD;
        Kh   = Ks;
        soff += 4 * ROW_BYTES;
    };

    for (int s = 0; s < 192; s += 2) {
        step(s,     P,  Nx);
        step(s + 1, Nx, P);
    }
}

extern "C" void kernel_launch(void* const* d_in, const int* in_sizes, int n_in,
                              void* d_out, int out_size, void* d_ws, size_t ws_size,
                              hipStream_t stream) {
    const float* x = (const float*)d_in[0];
    float* out     = (float*)d_out;
    const int B    = in_sizes[0] / BSTRIDE;
    const size_t GMAP_BYTES = (size_t)B * GSTR_O * sizeof(float);
    const size_t need_skew  = (size_t)B * (DSKEW_B + ESKEW_B) + GMAP_BYTES;

    if (ws_size >= need_skew) {
        char*  dsk = (char*)d_ws;
        char*  esk = dsk + (size_t)B * DSKEW_B;
        float* gm  = (float*)(esk + (size_t)B * ESKEW_B);
        skew_pre<<<dim3(16, B), dim3(256), 0, stream>>>(x, dsk);
        softdtw_dp_skew<<<dim3(B), dim3(64), 0, stream>>>(dsk, esk, gm);
        unskew_post<<<dim3(16, B), dim3(256), 0, stream>>>(esk, gm, out);
    } else {
        float* gm = (float*)d_ws;   // fallback needs only B*GSTR_Q*4 = 1 MB
        const int n4 = (B * BSTRIDE) / 4;
        softdtw_dp_direct<<<dim3(B), dim3(64), 0, stream>>>(x, out, gm);
        log_post_plain<<<dim3(2048), dim3(256), 0, stream>>>((float4*)out, gm, n4);
    }
}

// Round 19
// 116.910 us; speedup vs baseline: 1.1866x; 1.1866x over previous
//
#include <hip/hip_runtime.h>

#define N_DIM 512
#define M_DIM 512
#define NQUAD 128
#define TSTEPS 192          // even; 128 quads + 63 skew, padded
#define SLOT4 4096          // bf16 slot: 4 rows x 64 lanes x 16B
#define DDEPTH 6            // DP ring depth
#define RING6 (DDEPTH * SLOT4)
#define SIGMA_MAX (TSTEPS + DDEPTH)         // 198 input slots
#define BSTRIDE (N_DIM * M_DIM)
#define GSTRIDE (NQUAD * 64)
#define DSKEW_B ((size_t)SIGMA_MAX * SLOT4)
#define ESKEW_B ((size_t)TSTEPS * SLOT4)
#define LN2F 0.6931471805599453f
// fallback-path constants (f32 direct kernel)
#define DEPTH 4
#define SLOT_BYTES 8192
#define RING_BYTES (DEPTH * SLOT_BYTES)
#define ROW_BYTES 2048
#define ROW_MAX (511 * 2048)

#define AS1 __attribute__((address_space(1)))
#define AS3 __attribute__((address_space(3)))

__device__ inline unsigned pkbf16(float lo, float hi) {
    unsigned r; asm("v_cvt_pk_bf16_f32 %0, %1, %2" : "=v"(r) : "v"(lo), "v"(hi)); return r;
}
__device__ inline float ubf_lo(unsigned u) { return __int_as_float((int)(u << 16)); }
__device__ inline float ubf_hi(unsigned u) { return __int_as_float((int)(u & 0xffff0000u)); }

// ---- pass 1: exp(-D) -> bf16, skewed (slot, row-chunk, lane) layout ----
__global__ __launch_bounds__(256) void skew_pre(const float* __restrict__ D,
                                                char* __restrict__ Dsk) {
    const int b  = blockIdx.y;
    const int t0 = blockIdx.x << 3;
    __shared__ float4 tile[4096];                 // 32 rows x 128 f4
    const int tid = threadIdx.x;

    const float4* src = (const float4*)(D + (size_t)b * BSTRIDE) + ((size_t)t0 << 9);
    #pragma unroll
    for (int w = 0; w < 16; ++w) {
        const int idx = (w << 8) + tid;
        const float4 v = src[idx];
        tile[idx] = make_float4(__expf(-v.x), __expf(-v.y), __expf(-v.z), __expf(-v.w));
    }
    __syncthreads();

    char* dst = Dsk + (size_t)b * DSKEW_B;
    #pragma unroll
    for (int w = 0; w < 9; ++w) {
        const int w2 = (w << 8) + tid;            // [0, 2304)
        const int li = w2 & 7;
        const int ch = (w2 >> 3) & 3;             // row within quad
        const int si = w2 >> 5;                   // sigma - t0, [0, 72)
        const int lmin = max(0, si - 7);
        const int l = lmin + li;
        if (si < 71 && l <= min(63, si)) {
            const int ti = si - l;                // [0, 8)
            const int base = (((ti << 2) + ch) << 7) + (l << 1);
            const float4 a = tile[base];
            const float4 c = tile[base + 1];
            uint4 o;
            o.x = pkbf16(a.x, a.y); o.y = pkbf16(a.z, a.w);
            o.z = pkbf16(c.x, c.y); o.w = pkbf16(c.z, c.w);
            *(uint4*)(dst + (size_t)(t0 + si) * SLOT4 + (ch << 10) + (l << 4)) = o;
        }
    }
}

// ---- pass 3: un-skew bf16 E + R = g - log(E) ----
__global__ __launch_bounds__(256) void unskew_post(const char* __restrict__ Esk,
                                                   const float* __restrict__ gm,
                                                   float* __restrict__ R) {
    const int b  = blockIdx.y;
    const int t0 = blockIdx.x << 3;
    __shared__ float4 tile[4096];
    const int tid = threadIdx.x;

    const char* srcE = Esk + (size_t)b * ESKEW_B;
    #pragma unroll
    for (int w = 0; w < 9; ++w) {
        const int w2 = (w << 8) + tid;
        const int li = w2 & 7;
        const int ch = (w2 >> 3) & 3;
        const int si = w2 >> 5;
        const int lmin = max(0, si - 7);
        const int l = lmin + li;
        if (si < 71 && l <= min(63, si)) {
            const int ti = si - l;
            const uint4 v = *(const uint4*)(srcE + (size_t)(t0 + si) * SLOT4
                                            + (ch << 10) + (l << 4));
            const int base = (((ti << 2) + ch) << 7) + (l << 1);
            tile[base]     = make_float4(ubf_lo(v.x), ubf_hi(v.x), ubf_lo(v.y), ubf_hi(v.y));
            tile[base + 1] = make_float4(ubf_lo(v.z), ubf_hi(v.z), ubf_lo(v.w), ubf_hi(v.w));
        }
    }
    __syncthreads();

    float* dstR = R + (size_t)b * BSTRIDE;
    const float* gmb = gm + b * GSTRIDE;
    #pragma unroll
    for (int w = 0; w < 16; ++w) {
        const int idx = (w << 8) + tid;
        const int rit = idx >> 7;                 // 0..31
        const int c4  = idx & 127;
        const int tq  = t0 + (rit >> 2);
        const float g = gmb[(tq << 6) + (c4 >> 1)];
        const float4 v = tile[idx];
        *(float4*)(dstR + (((size_t)(t0 << 2) + rit) << 9) + (c4 << 2)) =
            make_float4(g - __logf(v.x), g - __logf(v.y), g - __logf(v.z), g - __logf(v.w));
    }
}

// ---- fallback post (plain layout) ----
__global__ __launch_bounds__(256) void log_post_plain(float4* __restrict__ E4,
                                                      const float* __restrict__ gm, int n4) {
    int i = blockIdx.x * blockDim.x + threadIdx.x;
    const int stride = gridDim.x * blockDim.x;
    for (; i < n4; i += stride) {
        const int b   = i >> 16;
        const int rem = i & 65535;
        const int row = rem >> 7;
        const int c4  = rem & 127;
        const float g = gm[(b << 13) + ((row >> 2) << 6) + (c4 >> 1)];
        const float4 v = E4[i];
        E4[i] = make_float4(g - __logf(v.x), g - __logf(v.y),
                            g - __logf(v.z), g - __logf(v.w));
    }
}

// DPP wave-shift-right-by-1 (lane 0 gets 0 = BIG boundary).
__device__ inline float shup1(float x) {
    int r = __builtin_amdgcn_update_dpp(0, __float_as_int(x), 0x138, 0xf, 0xf, true);
    return __int_as_float(r);
}
__device__ inline int shup1i(int x) {
    return __builtin_amdgcn_update_dpp(0, x, 0x138, 0xf, 0xf, true);
}
__device__ inline int fr_exp(float x) {
    int e; asm("v_frexp_exp_i32_f32 %0, %1" : "=v"(e) : "v"(x)); return e;
}
__device__ inline float ldx(float x, int k) {
    float r; asm("v_ldexp_f32 %0, %1, %2" : "=v"(r) : "v"(x), "v"(k)); return r;
}

// ---- pass 2: DP wave, bf16 plane, DIAGONAL-ORDER cascade (quad) ----
// Cells emitted in anti-diagonal order d = r+c: all cells on a diagonal are
// independent -> the 32-link row-sequential chain collapses to ~11 diagonal
// latencies with 4-wide ILP filling the bubbles.
__global__ __launch_bounds__(64, 1) void softdtw_dp_skew(const char* __restrict__ Dsk,
                                                         char* __restrict__ Esk,
                                                         float* __restrict__ gmap) {
    const int b = blockIdx.x;
    const int l = threadIdx.x;
    const int laneB16 = l << 4;

    const char* __restrict__ DskB = Dsk + (size_t)b * DSKEW_B;
    char*       __restrict__ EskB = Esk + (size_t)b * ESKEW_B;
    float*      __restrict__ gm   = gmap + (size_t)b * GSTRIDE;

    __shared__ char ring[RING6] __attribute__((aligned(16)));
    const unsigned ring_base = (unsigned)(size_t)(AS3 char*)ring;

    float Ep[8];
    #pragma unroll
    for (int k = 0; k < 8; ++k) Ep[k] = 0.0f;
    float fQ = 0.0f;
    int   KG = 0, KE = 0, Kh = 0;
    float expA7 = 0.0f, expB7 = 0.0f, expC7 = 0.0f, expD7 = 0.0f;
    float E7hD = 0.0f;

    int dsk_off = DDEPTH * SLOT4;   // global src for DMA at step s (slot s+6)
    int es_off  = 0;                // store offset for step s (slot s)
    unsigned dma_wo = 0;            // phys slot s % 6
    unsigned rd_wo  = SLOT4;        // phys slot (s+1) % 6

    uint4 P[4], Nx[4];
    #pragma unroll
    for (int ch = 0; ch < 4; ++ch)
        P[ch] = *(const uint4*)(DskB + ch * 1024 + laneB16);
    #pragma unroll
    for (int sig = 1; sig < DDEPTH; ++sig) {
        const char* gp = DskB + sig * SLOT4 + laneB16;
        #pragma unroll
        for (int ch = 0; ch < 4; ++ch)
            __builtin_amdgcn_global_load_lds((const AS1 void*)(gp + ch * 1024),
                                             (AS3 void*)(ring + sig * SLOT4 + ch * 1024),
                                             16, 0, 0);
    }
    asm volatile("s_waitcnt vmcnt(0)" ::: "memory");

    auto step = [&](int s, uint4 (&cur)[4], uint4 (&nxt)[4]) {
        // (1) DMA slot s+6 into phys slot s%6 (4 x 1KB coalesced)
        {
            const char* gp = DskB + dsk_off + laneB16;
            #pragma unroll
            for (int ch = 0; ch < 4; ++ch)
                __builtin_amdgcn_global_load_lds((const AS1 void*)(gp + ch * 1024),
                                                 (AS3 void*)(ring + dma_wo + ch * 1024), 16, 0, 0);
            dsk_off += SLOT4;
        }
        // (2) counted vmcnt: slot s+1's DMA batch (step s-5) has 45 newer ops
        asm volatile("s_waitcnt vmcnt(45)" ::: "memory");

        // (3) boundary from lane l-1 via DPP
        const float E7sA = shup1(expA7);
        const float E7sB = shup1(expB7);
        const float E7sC = shup1(expC7);
        const float E7sD = shup1(expD7);
        const int   Ks   = shup1i(KE);

        // (4) issue ds_read of next slot (4 x b128)
        const unsigned raddr = ring_base + rd_wo + (unsigned)laneB16;
        asm volatile("ds_read_b128 %0, %4 offset:0\n\t"
                     "ds_read_b128 %1, %4 offset:1024\n\t"
                     "ds_read_b128 %2, %4 offset:2048\n\t"
                     "ds_read_b128 %3, %4 offset:3072"
                     : "=&v"(nxt[0]), "=&v"(nxt[1]), "=&v"(nxt[2]), "=&v"(nxt[3])
                     : "v"(raddr));

        // (5) wait only for PREVIOUS step's 4 reads (cur); fence consumption
        asm volatile("s_waitcnt lgkmcnt(4)" ::: "memory");
        __builtin_amdgcn_sched_barrier(0);

        // (6) compute quad t = s - l (diagonal-order cascade)
        const int t = s - l;
        if (t >= 0 && t < NQUAD) {
            float end_[4][8];
            #pragma unroll
            for (int r = 0; r < 4; ++r) {
                end_[r][0] = ubf_lo(cur[r].x); end_[r][1] = ubf_hi(cur[r].x);
                end_[r][2] = ubf_lo(cur[r].y); end_[r][3] = ubf_hi(cur[r].y);
                end_[r][4] = ubf_lo(cur[r].z); end_[r][5] = ubf_hi(cur[r].z);
                end_[r][6] = ubf_lo(cur[r].w); end_[r][7] = ubf_hi(cur[r].w);
            }

            const bool is0    = (t == 0);
            const bool origin = is0 && (l == 0);
            int K = is0 ? (Ks - fr_exp(E7sA)) : KG;
            K = origin ? 0 : K;
            const float fq = is0 ? 0.0f : fQ;
            const int dKs = K - Ks;
            const int dKh = K - Kh;

            float eL[4];
            eL[0] = ldx(E7sA, dKs);
            eL[1] = ldx(E7sB, dKs);
            eL[2] = ldx(E7sC, dKs);
            eL[3] = ldx(E7sD, dKs);
            float eD0 = ldx(E7hD, dKh);
            eD0 = is0 ? 0.0f : eD0;
            eD0 = origin ? 1.0f : eD0;

            float Fp[8];
            #pragma unroll
            for (int c = 0; c < 8; ++c) Fp[c] = fq * Ep[c];

            // anti-diagonal cascade: all (r,c) with r+c == d are independent
            float Ev[4][8];
            #pragma unroll
            for (int d = 0; d <= 10; ++d) {
                #pragma unroll
                for (int r = 0; r < 4; ++r) {
                    const int c = d - r;
                    if (c >= 0 && c < 8) {
                        float q;
                        if (r == 0) q = (c == 0) ? (eD0 + Fp[0]) : (Fp[c - 1] + Fp[c]);
                        else        q = (c == 0) ? (eL[r - 1] + Ev[r - 1][0])
                                                 : (Ev[r - 1][c - 1] + Ev[r - 1][c]);
                        const float ein = (c == 0) ? eL[r] : Ev[r][c - 1];
                        Ev[r][c] = __builtin_fmaf(end_[r][c], ein, end_[r][c] * q);
                    }
                }
            }

            // pack + store (4 x 16B coalesced)
            char* sb = EskB + es_off + laneB16;
            #pragma unroll
            for (int r = 0; r < 4; ++r) {
                uint4 o;
                o.x = pkbf16(Ev[r][0], Ev[r][1]); o.y = pkbf16(Ev[r][2], Ev[r][3]);
                o.z = pkbf16(Ev[r][4], Ev[r][5]); o.w = pkbf16(Ev[r][6], Ev[r][7]);
                *(uint4*)(sb + r * 1024) = o;
            }
            gm[(t << 6) + l] = (float)K * LN2F;

            const int ed = fr_exp(Ev[3][0]);
            KG = K - ed;
            fQ = ldx(1.0f, -ed);
            KE = K;
            #pragma unroll
            for (int c = 0; c < 8; ++c) Ep[c] = Ev[3][c];
            expA7 = Ev[0][7]; expB7 = Ev[1][7]; expC7 = Ev[2][7]; expD7 = Ev[3][7];
        }

        // (7) history + ring offsets (wave-uniform)
        E7hD = E7sD;
        Kh   = Ks;
        es_off += SLOT4;
        dma_wo = (dma_wo == (DDEPTH - 1) * SLOT4) ? 0u : dma_wo + SLOT4;
        rd_wo  = (rd_wo  == (DDEPTH - 1) * SLOT4) ? 0u : rd_wo  + SLOT4;
    };

    for (int s = 0; s < TSTEPS; s += 2) {
        step(s,     P,  Nx);
        step(s + 1, Nx, P);
    }
}

// ---- fallback: direct DP (in-kernel exp, scattered), plain f32 layout ----
__global__ __launch_bounds__(64, 1) void softdtw_dp_direct(const float* __restrict__ Dsrc,
                                                           float* __restrict__ Eout,
                                                           float* __restrict__ gmap) {
    const int b     = blockIdx.x;
    const int l     = threadIdx.x;
    const int laneB = l << 5;
    const float* __restrict__ Db = Dsrc + (size_t)b * BSTRIDE;
    float*       __restrict__ Rb = Eout + (size_t)b * BSTRIDE;
    float*       __restrict__ gm = gmap + (size_t)b * GSTRIDE;
    __shared__ char ring[RING_BYTES] __attribute__((aligned(16)));
    const unsigned ring_base = (unsigned)(size_t)(AS3 char*)ring;

    float Ep[8];
    #pragma unroll
    for (int k = 0; k < 8; ++k) Ep[k] = 0.0f;
    float fQ = 0.0f;
    int KG = 0, KE = 0, Kh = 0;
    float expA7 = 0.0f, expB7 = 0.0f, expC7 = 0.0f, expD7 = 0.0f;
    float E7hD = 0.0f;
    int raw[4];
    #pragma unroll
    for (int k = 0; k < 4; ++k) raw[k] = (16 + k) * ROW_BYTES - (l << 13);
    int soff = -(l << 13);

    float4 P[8], Nx[8];
    #pragma unroll
    for (int row = 0; row < 4; ++row) {
        const int r = min(max(-4 * l + row, 0), N_DIM - 1);
        P[2 * row]     = *(const float4*)(Db + (size_t)r * M_DIM + (l << 3));
        P[2 * row + 1] = *(const float4*)(Db + (size_t)r * M_DIM + (l << 3) + 4);
    }
    #pragma unroll
    for (int sig = 1; sig < DEPTH; ++sig) {
        const unsigned wo = (unsigned)sig * SLOT_BYTES;
        #pragma unroll
        for (int k = 0; k < 4; ++k) {
            const int cl = min(max((4 * (sig - l) + k) * ROW_BYTES, 0), ROW_MAX);
            const char* gp = (const char*)Db + cl + laneB;
            __builtin_amdgcn_global_load_lds((const AS1 void*)gp,
                                             (AS3 void*)(ring + wo + (2 * k) * 1024), 16, 0, 0);
            __builtin_amdgcn_global_load_lds((const AS1 void*)(gp + 16),
                                             (AS3 void*)(ring + wo + (2 * k + 1) * 1024), 16, 0, 0);
        }
    }
    asm volatile("s_waitcnt vmcnt(0)" ::: "memory");

    auto rowfma = [&](const float* endv, float eLeft, const float* Q, float* E) {
        float e = eLeft;
        #pragma unroll
        for (int c = 0; c < 8; ++c) {
            e = __builtin_fmaf(endv[c], e, endv[c] * Q[c]);
            E[c] = e;
        }
    };

    auto step = [&](int s, float4 (&cur)[8], float4 (&nxt)[8]) {
        {
            const unsigned wo = ((unsigned)(s + DEPTH) & (DEPTH - 1)) * SLOT_BYTES;
            #pragma unroll
            for (int k = 0; k < 4; ++k) {
                const int cl = min(max(raw[k], 0), ROW_MAX);
                const char* gp = (const char*)Db + cl + laneB;
                __builtin_amdgcn_global_load_lds((const AS1 void*)gp,
                                                 (AS3 void*)(ring + wo + (2 * k) * 1024), 16, 0, 0);
                __builtin_amdgcn_global_load_lds((const AS1 void*)(gp + 16),
                                                 (AS3 void*)(ring + wo + (2 * k + 1) * 1024), 16, 0, 0);
                raw[k] += 4 * ROW_BYTES;
            }
        }
        asm volatile("s_waitcnt vmcnt(51)" ::: "memory");
        const float E7sA = shup1(expA7);
        const float E7sB = shup1(expB7);
        const float E7sC = shup1(expC7);
        const float E7sD = shup1(expD7);
        const int   Ks   = shup1i(KE);
        const unsigned raddr = ring_base
                             + (unsigned)((s + 1) & (DEPTH - 1)) * SLOT_BYTES
                             + (unsigned)l * 16u;
        asm volatile("ds_read_b128 %0, %8 offset:0\n\t"
                     "ds_read_b128 %1, %8 offset:1024\n\t"
                     "ds_read_b128 %2, %8 offset:2048\n\t"
                     "ds_read_b128 %3, %8 offset:3072\n\t"
                     "ds_read_b128 %4, %8 offset:4096\n\t"
                     "ds_read_b128 %5, %8 offset:5120\n\t"
                     "ds_read_b128 %6, %8 offset:6144\n\t"
                     "ds_read_b128 %7, %8 offset:7168"
                     : "=&v"(nxt[0]), "=&v"(nxt[1]), "=&v"(nxt[2]), "=&v"(nxt[3]),
                       "=&v"(nxt[4]), "=&v"(nxt[5]), "=&v"(nxt[6]), "=&v"(nxt[7])
                     : "v"(raddr));
        asm volatile("s_waitcnt lgkmcnt(8)" ::: "memory");
        __builtin_amdgcn_sched_barrier(0);
        const int t = s - l;
        if (t >= 0 && t < NQUAD) {
            const float endA[8] = {__expf(-cur[0].x), __expf(-cur[0].y), __expf(-cur[0].z), __expf(-cur[0].w),
                                   __expf(-cur[1].x), __expf(-cur[1].y), __expf(-cur[1].z), __expf(-cur[1].w)};
            const float endB[8] = {__expf(-cur[2].x), __expf(-cur[2].y), __expf(-cur[2].z), __expf(-cur[2].w),
                                   __expf(-cur[3].x), __expf(-cur[3].y), __expf(-cur[3].z), __expf(-cur[3].w)};
            const float endC[8] = {__expf(-cur[4].x), __expf(-cur[4].y), __expf(-cur[4].z), __expf(-cur[4].w),
                                   __expf(-cur[5].x), __expf(-cur[5].y), __expf(-cur[5].z), __expf(-cur[5].w)};
            const float endD[8] = {__expf(-cur[6].x), __expf(-cur[6].y), __expf(-cur[6].z), __expf(-cur[6].w),
                                   __expf(-cur[7].x), __expf(-cur[7].y), __expf(-cur[7].z), __expf(-cur[7].w)};
            const bool is0    = (t == 0);
            const bool origin = is0 && (l == 0);
            int K = is0 ? (Ks - fr_exp(E7sA)) : KG;
            K = origin ? 0 : K;
            const float fq = is0 ? 0.0f : fQ;
            const int dKs = K - Ks;
            const int dKh = K - Kh;
            const float eLA = ldx(E7sA, dKs);
            const float eLB = ldx(E7sB, dKs);
            const float eLC = ldx(E7sC, dKs);
            const float eLD = ldx(E7sD, dKs);
            float eDA0 = ldx(E7hD, dKh);
            eDA0 = is0 ? 0.0f : eDA0;
            eDA0 = origin ? 1.0f : eDA0;
            float QA[8];
            QA[0] = eDA0 + fq * Ep[0];
            #pragma unroll
            for (int c = 1; c < 8; ++c) QA[c] = fq * (Ep[c - 1] + Ep[c]);
            float EA[8]; rowfma(endA, eLA, QA, EA);
            float QB[8];
            QB[0] = eLA + EA[0];
            #pragma unroll
            for (int c = 1; c < 8; ++c) QB[c] = EA[c - 1] + EA[c];
            float EB[8]; rowfma(endB, eLB, QB, EB);
            float QC[8];
            QC[0] = eLB + EB[0];
            #pragma unroll
            for (int c = 1; c < 8; ++c) QC[c] = EB[c - 1] + EB[c];
            float EC[8]; rowfma(endC, eLC, QC, EC);
            float QD[8];
            QD[0] = eLC + EC[0];
            #pragma unroll
            for (int c = 1; c < 8; ++c) QD[c] = EC[c - 1] + EC[c];
            float ED[8]; rowfma(endD, eLD, QD, ED);
            char* sb  = (char*)Rb + soff + laneB;
            char* sb2 = sb + 4096;
            *(float4*)(sb)         = make_float4(EA[0], EA[1], EA[2], EA[3]);
            *(float4*)(sb + 16)    = make_float4(EA[4], EA[5], EA[6], EA[7]);
            *(float4*)(sb + 2048)  = make_float4(EB[0], EB[1], EB[2], EB[3]);
            *(float4*)(sb + 2064)  = make_float4(EB[4], EB[5], EB[6], EB[7]);
            *(float4*)(sb2)        = make_float4(EC[0], EC[1], EC[2], EC[3]);
            *(float4*)(sb2 + 16)   = make_float4(EC[4], EC[5], EC[6], EC[7]);
            *(float4*)(sb2 + 2048) = make_float4(ED[0], ED[1], ED[2], ED[3]);
            *(float4*)(sb2 + 2064) = make_float4(ED[4], ED[5], ED[6], ED[7]);
            gm[(t << 6) + l] = (float)K * LN2F;
            const int ed = fr_exp(ED[0]);
            KG = K - ed;
            fQ = ldx(1.0f, -ed);
            KE = K;
            #pragma unroll
            for (int c = 0; c < 8; ++c) Ep[c] = ED[c];
            expA7 = EA[7]; expB7 = EB[7]; expC7 = EC[7]; expD7 = ED[7];
        }
        E7hD = E7sD;
        Kh   = Ks;
        soff += 4 * ROW_BYTES;
    };

    for (int s = 0; s < TSTEPS; s += 2) {
        step(s,     P,  Nx);
        step(s + 1, Nx, P);
    }
}

extern "C" void kernel_launch(void* const* d_in, const int* in_sizes, int n_in,
                              void* d_out, int out_size, void* d_ws, size_t ws_size,
                              hipStream_t stream) {
    const float* x = (const float*)d_in[0];
    float* out     = (float*)d_out;
    const int B    = in_sizes[0] / BSTRIDE;
    const size_t GMAP_BYTES = (size_t)B * GSTRIDE * sizeof(float);
    const size_t need_skew  = (size_t)B * (DSKEW_B + ESKEW_B) + GMAP_BYTES;

    if (ws_size >= need_skew) {
        char*  dsk = (char*)d_ws;
        char*  esk = dsk + (size_t)B * DSKEW_B;
        float* gm  = (float*)(esk + (size_t)B * ESKEW_B);
        skew_pre<<<dim3(16, B), dim3(256), 0, stream>>>(x, dsk);
        softdtw_dp_skew<<<dim3(B), dim3(64), 0, stream>>>(dsk, esk, gm);
        unskew_post<<<dim3(16, B), dim3(256), 0, stream>>>(esk, gm, out);
    } else {
        float* gm = (float*)d_ws;   // needs only 1 MB
        const int n4 = (B * BSTRIDE) / 4;
        softdtw_dp_direct<<<dim3(B), dim3(64), 0, stream>>>(x, out, gm);
        log_post_plain<<<dim3(2048), dim3(256), 0, stream>>>((float4*)out, gm, n4);
    }
}